// Round 4
// baseline (729.493 us; speedup 1.0000x reference)
//
#include <hip/hip_runtime.h>

typedef unsigned short u16;
typedef __attribute__((ext_vector_type(4))) short short4v;
typedef __attribute__((ext_vector_type(8))) short short8;
typedef __attribute__((ext_vector_type(4))) float f32x4;

// ---------- helpers ----------
__device__ __forceinline__ float bf2f(u16 v) {
    return __uint_as_float(((unsigned)v) << 16);
}
__device__ __forceinline__ u16 f2bf(float f) {
    unsigned u = __float_as_uint(f);
    return (u16)((u + 0x7FFFu + ((u >> 16) & 1u)) >> 16);
}
__device__ __forceinline__ void gload16(const void* g, void* l) {
    __builtin_amdgcn_global_load_lds(
        (const __attribute__((address_space(1))) void*)g,
        (__attribute__((address_space(3))) void*)l, 16, 0, 0);
}
__device__ __forceinline__ float sigm(float x) {
    return 1.0f / (1.0f + __expf(-x));
}
__device__ __forceinline__ float tanh_fast(float x) {
    return 1.0f - 2.0f / (__expf(2.0f * x) + 1.0f);  // saturates for large |x|
}

// ---------- pack x: fp32 [2048][4096] -> bf16 Abuf[b][k], k in [0,2048) (transpose) ----------
__global__ __launch_bounds__(256) void k_pack_x(const float* __restrict__ x,
                                                u16* __restrict__ Abuf) {
    __shared__ float tile[32][33];
    const int tid = threadIdx.x;
    const int tx = tid & 31, ty = tid >> 5;  // 32 x 8
    const int tk = blockIdx.x & 63;          // 2048/32 k-tiles
    const int tb = blockIdx.x >> 6;          // 4096/32 b-tiles
#pragma unroll
    for (int i = 0; i < 4; ++i) {
        int row = ty + i * 8;  // local k
        tile[row][tx] = x[(size_t)(tk * 32 + row) * 4096 + tb * 32 + tx];
    }
    __syncthreads();
#pragma unroll
    for (int i = 0; i < 4; ++i) {
        int row = ty + i * 8;  // local b
        Abuf[(size_t)(tb * 32 + row) * 4096 + tk * 32 + tx] = f2bf(tile[tx][row]);
    }
}

// ---------- pack h: fp32 [4096][2048] -> bf16 Abuf[b][2048+k] ----------
__global__ __launch_bounds__(256) void k_pack_h(const float* __restrict__ h,
                                                u16* __restrict__ Abuf) {
    const int t = blockIdx.x * 256 + threadIdx.x;  // 2,097,152 threads
    const size_t e = (size_t)t * 4;                // 8,388,608 elems
    const int b = (int)(e >> 11), k = (int)(e & 2047);
    f32x4 v = *(const f32x4*)(h + e);
    short4v o;
#pragma unroll
    for (int j = 0; j < 4; ++j) o[j] = (short)f2bf(v[j]);
    *(short4v*)(Abuf + (size_t)b * 4096 + 2048 + k) = o;
}

// ---------- pack all 8 weights, gate-interleaved 16-row groups ----------
// Bbuf row for weight-row n of gate z: (n>>4)*64 + z*16 + (n&15); Wi at k<2048, Wh at k>=2048
__global__ __launch_bounds__(256) void k_pack_w(
    const float* __restrict__ wi_i, const float* __restrict__ wi_f,
    const float* __restrict__ wi_g, const float* __restrict__ wi_o,
    const float* __restrict__ wh_i, const float* __restrict__ wh_f,
    const float* __restrict__ wh_g, const float* __restrict__ wh_o,
    u16* __restrict__ Bbuf) {
    const int widx = blockIdx.x >> 12;  // 0..7: which weight matrix
    const int z = widx >> 1, half = widx & 1;
    const float* w = widx == 0 ? wi_i : widx == 1 ? wh_i
                   : widx == 2 ? wi_f : widx == 3 ? wh_f
                   : widx == 4 ? wi_g : widx == 5 ? wh_g
                   : widx == 6 ? wi_o : wh_o;
    const int t = (blockIdx.x & 4095) * 256 + threadIdx.x;
    const size_t e = (size_t)t * 4;                 // 4,194,304 elems per matrix
    const int n = (int)(e >> 11), k = (int)(e & 2047);
    f32x4 v = *(const f32x4*)(w + e);
    short4v o;
#pragma unroll
    for (int j = 0; j < 4; ++j) o[j] = (short)f2bf(v[j]);
    const int dstrow = (n >> 4) * 64 + z * 16 + (n & 15);
    *(short4v*)(Bbuf + (size_t)dstrow * 4096 + half * 2048 + k) = o;
}

// ---------- combine biases ----------
__global__ __launch_bounds__(256) void k_bias(
    const float* __restrict__ b_ii, const float* __restrict__ b_hi,
    const float* __restrict__ b_if, const float* __restrict__ b_hf,
    const float* __restrict__ b_ig, const float* __restrict__ b_hg,
    const float* __restrict__ b_io, const float* __restrict__ b_ho,
    float* __restrict__ bc) {
    const int n = blockIdx.x * 256 + threadIdx.x;  // 2048 threads
    bc[n] = b_ii[n] + b_hi[n];
    bc[2048 + n] = b_if[n] + b_hf[n];
    bc[4096 + n] = b_ig[n] + b_hg[n];
    bc[6144 + n] = b_io[n] + b_ho[n];
}

// ---------- fused GEMM + LSTM cell (m97 structure, 128x128 tile, BK=32) ----------
// A = Abuf [4096][4096] bf16; B = Bbuf [8192][4096] bf16 gate-interleaved.
// Each block: 128 batch rows x 32 hidden cols x 4 gates -> h,c fp32 to out.
__global__ __launch_bounds__(256) void k_gemm(
    const u16* __restrict__ A, const u16* __restrict__ B,
    const float* __restrict__ c_in, const float* __restrict__ bc,
    float* __restrict__ out) {
    __shared__ __attribute__((aligned(16))) u16 sm[8192];  // A bytes [0,8192), B [8192,16384)

    const int tid = threadIdx.x;
    const int bid = blockIdx.x;
    const int bm = bid >> 6;   // 32 m-blocks (batch/128)
    const int bn = bid & 63;   // 64 n-blocks (8192/128 interleaved rows)
    const int m0 = bm * 128;
    const int n0 = bn * 128;

    const int c0 = tid, c1 = tid + 256;           // 16B chunks (512 per tile)
    const int rA0 = c0 >> 2, kA0 = (c0 & 3) * 8;
    const int rA1 = c1 >> 2, kA1 = (c1 & 3) * 8;

    const int wid = tid >> 6, lane = tid & 63;
    const int wm = wid >> 1, wn = wid & 1;        // 2x2 waves over 128x128
    const int lrow = lane & 15, kc = lane >> 4;

    f32x4 acc[4][4] = {};

#pragma unroll 1
    for (int kt = 0; kt < 128; ++kt) {
        const int kk = kt * 32;
        __syncthreads();
        gload16(A + (size_t)(m0 + rA0) * 4096 + kk + kA0, (char*)sm + c0 * 16);
        gload16(B + (size_t)(n0 + rA0) * 4096 + kk + kA0, (char*)sm + 8192 + c0 * 16);
        gload16(A + (size_t)(m0 + rA1) * 4096 + kk + kA1, (char*)sm + c1 * 16);
        gload16(B + (size_t)(n0 + rA1) * 4096 + kk + kA1, (char*)sm + 8192 + c1 * 16);
        __syncthreads();

        short8 a[4], b[4];
#pragma unroll
        for (int i = 0; i < 4; ++i)
            a[i] = *(const short8*)((const char*)sm +
                    ((wm * 64 + i * 16 + lrow) * 32 + kc * 8) * 2);
#pragma unroll
        for (int j = 0; j < 4; ++j)
            b[j] = *(const short8*)((const char*)sm + 8192 +
                    ((wn * 64 + j * 16 + lrow) * 32 + kc * 8) * 2);
#pragma unroll
        for (int i = 0; i < 4; ++i)
#pragma unroll
            for (int j = 0; j < 4; ++j)
                acc[i][j] = __builtin_amdgcn_mfma_f32_16x16x32_bf16(
                    a[i], b[j], acc[i][j], 0, 0, 0);
    }

    // Fused epilogue. Interleave math: B row rb = n0+wn*64+j*16+lrow,
    // g = rb>>4 = bn*8+wn*4+j -> gate = g&3 = j; hc = (g>>2)*16+lrow = (bn*2+wn)*16+lrow.
    // D mapping (m89): batch row = m0+wm*64+i*16+(lane>>4)*4+reg, N index uses lane&15.
    const int hc = (bn * 2 + wn) * 16 + lrow;
    const float bi = bc[hc], bfv = bc[2048 + hc], bg = bc[4096 + hc], bo = bc[6144 + hc];
    float* outh = out;              // [4096][2048]
    float* outc = out + 8388608u;   // [4096][2048]
#pragma unroll
    for (int i = 0; i < 4; ++i) {
        const int b0 = m0 + wm * 64 + i * 16 + kc * 4;
#pragma unroll
        for (int r = 0; r < 4; ++r) {
            const int b = b0 + r;
            const size_t idx = (size_t)b * 2048 + hc;
            float I = acc[i][0][r] + bi;
            float F = acc[i][1][r] + bfv;
            float Gv = acc[i][2][r] + bg;
            float O = acc[i][3][r] + bo;
            float cn = sigm(F) * c_in[idx] + sigm(I) * tanh_fast(Gv);
            float hn = sigm(O) * tanh_fast(cn);
            outh[idx] = hn;
            outc[idx] = cn;
        }
    }
}

// ---------- launcher ----------
extern "C" void kernel_launch(void* const* d_in, const int* in_sizes, int n_in,
                              void* d_out, int out_size, void* d_ws, size_t ws_size,
                              hipStream_t stream) {
    const float* x = (const float*)d_in[0];  // [2048][4096]
    const float* h = (const float*)d_in[1];  // [4096][2048]
    const float* c = (const float*)d_in[2];  // [4096][2048]

    // workspace: Abuf bf16 [4096][4096] @0 (33.5MB); Bbuf bf16 [8192][4096] @33.5MB (67MB);
    // bc fp32 [4][2048] @100.7MB. Total ~100.7MB.
    u16* Abuf = (u16*)d_ws;
    u16* Bbuf = Abuf + 16777216u;
    float* bcp = (float*)(Bbuf + 33554432u);
    float* out = (float*)d_out;

    k_pack_x<<<8192, 256, 0, stream>>>(x, Abuf);
    k_pack_h<<<8192, 256, 0, stream>>>(h, Abuf);
    k_pack_w<<<32768, 256, 0, stream>>>(
        (const float*)d_in[3], (const float*)d_in[4], (const float*)d_in[5],
        (const float*)d_in[6], (const float*)d_in[7], (const float*)d_in[8],
        (const float*)d_in[9], (const float*)d_in[10], Bbuf);
    k_bias<<<8, 256, 0, stream>>>((const float*)d_in[11], (const float*)d_in[12],
                                  (const float*)d_in[13], (const float*)d_in[14],
                                  (const float*)d_in[15], (const float*)d_in[16],
                                  (const float*)d_in[17], (const float*)d_in[18], bcp);
    k_gemm<<<2048, 256, 0, stream>>>(Abuf, Bbuf, c, bcp, out);
}